// Round 8
// baseline (663.499 us; speedup 1.0000x reference)
//
#include <hip/hip_runtime.h>
#include <math.h>

// ---------------- CSR build ----------------

__global__ void zero_ints(int* __restrict__ a, int n) {
  int i = blockIdx.x * blockDim.x + threadIdx.x;
  if (i < n) a[i] = 0;
}

__global__ void count_dst(const int* __restrict__ dst, int* __restrict__ cnt, int E) {
  int e = blockIdx.x * blockDim.x + threadIdx.x;
  if (e < E) atomicAdd(&cnt[dst[e]], 1);
}

__global__ __launch_bounds__(1024) void scan_rowptr(const int* __restrict__ cnt,
                                                    int* __restrict__ rowptr, int N) {
  __shared__ int part[1024];
  int tid = threadIdx.x;
  int per = (N + 1023) >> 10;
  int start = tid * per;
  int stop = start + per; if (stop > N) stop = N;
  int sum = 0;
  for (int i = start; i < stop; ++i) sum += cnt[i];
  part[tid] = sum;
  __syncthreads();
  // Hillis-Steele inclusive scan
  for (int off = 1; off < 1024; off <<= 1) {
    int v = (tid >= off) ? part[tid - off] : 0;
    __syncthreads();
    part[tid] += v;
    __syncthreads();
  }
  int run = (tid == 0) ? 0 : part[tid - 1];
  for (int i = start; i < stop; ++i) { rowptr[i] = run; run += cnt[i]; }
  if (tid == 1023) rowptr[N] = part[1023];
}

__global__ void compute_dinv(const int* __restrict__ cnt, float* __restrict__ dinv, int N) {
  int i = blockIdx.x * blockDim.x + threadIdx.x;
  if (i < N) dinv[i] = rsqrtf((float)cnt[i] + 1.0f);  // +1 self-loop; deg>=1 always
}

__global__ void fill_csr(const int* __restrict__ src, const int* __restrict__ dst,
                         const float* __restrict__ dinv, int* __restrict__ cursor,
                         const int* __restrict__ rowptr, int* __restrict__ csr_src,
                         float* __restrict__ csr_w, int E) {
  int e = blockIdx.x * blockDim.x + threadIdx.x;
  if (e >= E) return;
  int d = dst[e], s = src[e];
  int pos = atomicAdd(&cursor[d], 1);
  int idx = rowptr[d] + pos;
  csr_src[idx] = s;
  csr_w[idx] = dinv[s] * dinv[d];
}

// ---------------- dense transform: C[N,128] = A[N,128] @ W[128,128] ----------------
// 32 rows/block, 256 threads, thread computes 4x4 register tile.
// W staged in two 64-row k-halves (32KB) + A tile (16KB) -> 48KB LDS.

__global__ __launch_bounds__(256) void gemm_x128(const float* __restrict__ A,
                                                 const float* __restrict__ W,
                                                 float* __restrict__ C, int N) {
  __shared__ float Ws[64 * 128];   // 32KB, current k-half
  __shared__ float As[32 * 128];   // 16KB
  const float4* A4 = (const float4*)A;
  const float4* W4 = (const float4*)W;
  float4* Ws4 = (float4*)Ws;
  float4* As4 = (float4*)As;
  int row0 = blockIdx.x * 32;
  // stage A tile (1024 float4)
#pragma unroll
  for (int i = 0; i < 4; ++i) {
    int idx = threadIdx.x + 256 * i;
    int r = idx >> 5, k4 = idx & 31;
    int grow = row0 + r;
    float4 v = make_float4(0.f, 0.f, 0.f, 0.f);
    if (grow < N) v = A4[(size_t)grow * 32 + k4];
    As4[idx] = v;
  }
  int cg = threadIdx.x & 31;   // col group (4 cols)
  int rg = threadIdx.x >> 5;   // row group (4 rows)
  int r0 = rg * 4;
  float acc[4][4] = {};
  for (int half = 0; half < 2; ++half) {
    __syncthreads();
    // stage 64 rows of W (2048 float4)
#pragma unroll
    for (int i = 0; i < 8; ++i) {
      int idx = threadIdx.x + 256 * i;
      Ws4[idx] = W4[half * 2048 + idx];
    }
    __syncthreads();
#pragma unroll
    for (int k4 = 0; k4 < 16; ++k4) {
      float4 a[4], w[4];
#pragma unroll
      for (int i = 0; i < 4; ++i) a[i] = As4[(r0 + i) * 32 + half * 16 + k4];
#pragma unroll
      for (int j = 0; j < 4; ++j) w[j] = Ws4[(k4 * 4 + j) * 32 + cg];
#pragma unroll
      for (int i = 0; i < 4; ++i) {
        acc[i][0] += a[i].x * w[0].x + a[i].y * w[1].x + a[i].z * w[2].x + a[i].w * w[3].x;
        acc[i][1] += a[i].x * w[0].y + a[i].y * w[1].y + a[i].z * w[2].y + a[i].w * w[3].y;
        acc[i][2] += a[i].x * w[0].z + a[i].y * w[1].z + a[i].z * w[2].z + a[i].w * w[3].z;
        acc[i][3] += a[i].x * w[0].w + a[i].y * w[1].w + a[i].z * w[2].w + a[i].w * w[3].w;
      }
    }
  }
  float4* C4 = (float4*)C;
#pragma unroll
  for (int i = 0; i < 4; ++i) {
    int grow = row0 + r0 + i;
    if (grow < N)
      C4[(size_t)grow * 32 + cg] = make_float4(acc[i][0], acc[i][1], acc[i][2], acc[i][3]);
  }
}

// ---------------- aggregation: out = S*H + b  (gather-CSR, wave per dst node) ----------------

__global__ __launch_bounds__(256) void agg_csr(const float* __restrict__ H,
                                               const int* __restrict__ csr_src,
                                               const float* __restrict__ csr_w,
                                               const int* __restrict__ rowptr,
                                               const float* __restrict__ dinv,
                                               const float* __restrict__ b,
                                               float* __restrict__ out, int N) {
  int node = blockIdx.x * 4 + (threadIdx.x >> 6);
  if (node >= N) return;
  int lane = threadIdx.x & 63;
  int beg = rowptr[node], end = rowptr[node + 1];
  float di = dinv[node];
  float sw = di * di;  // self-loop norm
  float2 h0 = *(const float2*)(H + (size_t)node * 128 + 2 * lane);
  float ax = h0.x * sw, ay = h0.y * sw;
  int i = beg;
  for (; i + 2 <= end; i += 2) {
    int s0 = csr_src[i], s1 = csr_src[i + 1];
    float w0 = csr_w[i], w1 = csr_w[i + 1];
    float2 v0 = *(const float2*)(H + (size_t)s0 * 128 + 2 * lane);
    float2 v1 = *(const float2*)(H + (size_t)s1 * 128 + 2 * lane);
    ax += v0.x * w0 + v1.x * w1;
    ay += v0.y * w0 + v1.y * w1;
  }
  if (i < end) {
    int s0 = csr_src[i];
    float w0 = csr_w[i];
    float2 v0 = *(const float2*)(H + (size_t)s0 * 128 + 2 * lane);
    ax += v0.x * w0;
    ay += v0.y * w0;
  }
  float2 bb = *(const float2*)(b + 2 * lane);
  *(float2*)(out + (size_t)node * 128 + 2 * lane) = make_float2(ax + bb.x, ay + bb.y);
}

// ---------------- head: fold Wp1@Wp2, then per-node 128->16 + log_softmax ----------------

__global__ __launch_bounds__(256) void fuse_w(const float* __restrict__ Wp1,
                                              const float* __restrict__ bp1,
                                              const float* __restrict__ Wp2,
                                              const float* __restrict__ bp2,
                                              float* __restrict__ Wf, float* __restrict__ bf) {
  int tid = threadIdx.x;
  for (int o = tid; o < 2048; o += 256) {
    int r = o >> 4, j = o & 15;
    float s = 0.f;
    for (int k = 0; k < 128; ++k) s += Wp1[r * 128 + k] * Wp2[k * 16 + j];
    Wf[o] = s;
  }
  if (tid < 16) {
    float s = bp2[tid];
    for (int k = 0; k < 128; ++k) s += bp1[k] * Wp2[k * 16 + tid];
    bf[tid] = s;
  }
}

__global__ __launch_bounds__(256) void proj_kernel(const float* __restrict__ emb,
                                                   const float* __restrict__ Wf,
                                                   const float* __restrict__ bf,
                                                   float* __restrict__ out, int N) {
  __shared__ float Ws[2048];
  __shared__ float bfs[16];
  for (int i = threadIdx.x; i < 2048; i += 256) Ws[i] = Wf[i];
  if (threadIdx.x < 16) bfs[threadIdx.x] = bf[threadIdx.x];
  __syncthreads();
  int node = blockIdx.x * 4 + (threadIdx.x >> 6);
  if (node >= N) return;
  int lane = threadIdx.x & 63;
  int j = lane & 15, g = lane >> 4;   // lane owns output j, k-range [32g, 32g+32)
  const float* er = emb + (size_t)node * 128 + g * 32;
  float p = 0.f;
#pragma unroll
  for (int k = 0; k < 32; ++k) p += er[k] * Ws[(g * 32 + k) * 16 + j];
  p += __shfl_xor(p, 16);
  p += __shfl_xor(p, 32);
  p += bfs[j];
  float mx = p;
#pragma unroll
  for (int o = 1; o < 16; o <<= 1) mx = fmaxf(mx, __shfl_xor(mx, o));
  float ex = expf(p - mx);
  float sm = ex;
#pragma unroll
  for (int o = 1; o < 16; o <<= 1) sm += __shfl_xor(sm, o);
  float res = p - mx - logf(sm);
  if (lane < 16) out[(size_t)node * 16 + j] = res;
}

// ---------------- launch ----------------

extern "C" void kernel_launch(void* const* d_in, const int* in_sizes, int n_in,
                              void* d_out, int out_size, void* d_ws, size_t ws_size,
                              hipStream_t stream) {
  const float* x   = (const float*)d_in[0];
  const int*   ei  = (const int*)d_in[1];
  const float* W1  = (const float*)d_in[2];
  const float* b1  = (const float*)d_in[3];
  const float* W2  = (const float*)d_in[4];
  const float* b2  = (const float*)d_in[5];
  const float* W3  = (const float*)d_in[6];
  const float* b3  = (const float*)d_in[7];
  const float* Wp1 = (const float*)d_in[8];
  const float* bp1 = (const float*)d_in[9];
  const float* Wp2 = (const float*)d_in[10];
  const float* bp2 = (const float*)d_in[11];

  const int N = in_sizes[0] / 128;
  const int E = in_sizes[1] / 2;
  const int* src = ei;       // edge_index[0]
  const int* dst = ei + E;   // edge_index[1]

  float* out    = (float*)d_out;
  float* emb    = out;                       // [N,128] embedding slice, also ping buffer
  float* scores = out + (size_t)N * 128;     // [N,16]

  char* w = (char*)d_ws;
  auto alloc = [&](size_t bytes) {
    char* p = w;
    w += (bytes + 255) & ~(size_t)255;
    return p;
  };
  int*   cnt     = (int*)alloc((size_t)N * 4);
  int*   cursor  = (int*)alloc((size_t)N * 4);
  int*   rowptr  = (int*)alloc(((size_t)N + 1) * 4);
  float* dinv    = (float*)alloc((size_t)N * 4);
  int*   csr_src = (int*)alloc((size_t)E * 4);
  float* csr_w   = (float*)alloc((size_t)E * 4);
  float* H       = (float*)alloc((size_t)N * 128 * 4);
  float* Wf      = (float*)alloc(2048 * 4);
  float* bf      = (float*)alloc(16 * 4);

  int gN = (N + 255) / 256;
  int gE = (E + 255) / 256;
  zero_ints<<<gN, 256, 0, stream>>>(cnt, N);
  zero_ints<<<gN, 256, 0, stream>>>(cursor, N);
  count_dst<<<gE, 256, 0, stream>>>(dst, cnt, E);
  scan_rowptr<<<1, 1024, 0, stream>>>(cnt, rowptr, N);
  compute_dinv<<<gN, 256, 0, stream>>>(cnt, dinv, N);
  fill_csr<<<gE, 256, 0, stream>>>(src, dst, dinv, cursor, rowptr, csr_src, csr_w, E);
  fuse_w<<<1, 256, 0, stream>>>(Wp1, bp1, Wp2, bp2, Wf, bf);

  int gemm_grid = (N + 31) / 32;
  int node_grid = (N + 3) / 4;
  gemm_x128<<<gemm_grid, 256, 0, stream>>>(x, W1, H, N);
  agg_csr<<<node_grid, 256, 0, stream>>>(H, csr_src, csr_w, rowptr, dinv, b1, emb, N);
  gemm_x128<<<gemm_grid, 256, 0, stream>>>(emb, W2, H, N);
  agg_csr<<<node_grid, 256, 0, stream>>>(H, csr_src, csr_w, rowptr, dinv, b2, emb, N);
  gemm_x128<<<gemm_grid, 256, 0, stream>>>(emb, W3, H, N);
  agg_csr<<<node_grid, 256, 0, stream>>>(H, csr_src, csr_w, rowptr, dinv, b3, emb, N);
  proj_kernel<<<node_grid, 256, 0, stream>>>(emb, Wf, bf, scores, N);
}

// Round 9
// 576.998 us; speedup vs baseline: 1.1499x; 1.1499x over previous
//
#include <hip/hip_runtime.h>
#include <math.h>

// ---------------- CSR build ----------------

__global__ void zero_ints(int* __restrict__ a, int n) {
  int i = blockIdx.x * blockDim.x + threadIdx.x;
  if (i < n) a[i] = 0;
}

__global__ void count_dst(const int* __restrict__ dst, int* __restrict__ cnt, int E) {
  int e = blockIdx.x * blockDim.x + threadIdx.x;
  if (e < E) atomicAdd(&cnt[dst[e]], 1);
}

// ---- 3-phase multi-block scan (replaces 75us single-block scan_rowptr) ----
// Requires ceil(N/256) <= 256, i.e. N <= 65536 (N = 50000 here).

__global__ __launch_bounds__(256) void scan_blocksums(const int* __restrict__ cnt,
                                                      int* __restrict__ bsum,
                                                      int N, int chunk) {
  __shared__ int red[256];
  int t = threadIdx.x, b = blockIdx.x;
  int i = b * chunk + t;
  red[t] = (t < chunk && i < N) ? cnt[i] : 0;
  __syncthreads();
#pragma unroll
  for (int off = 128; off > 0; off >>= 1) {
    if (t < off) red[t] += red[t + off];
    __syncthreads();
  }
  if (t == 0) bsum[b] = red[0];
}

__global__ __launch_bounds__(256) void scan_offsets(const int* __restrict__ bsum,
                                                    int* __restrict__ boff,
                                                    int* __restrict__ rowptr, int N) {
  __shared__ int s[256];
  int t = threadIdx.x;
  int v = bsum[t];
  s[t] = v;
  __syncthreads();
#pragma unroll
  for (int off = 1; off < 256; off <<= 1) {
    int u = (t >= off) ? s[t - off] : 0;
    __syncthreads();
    s[t] += u;
    __syncthreads();
  }
  boff[t] = s[t] - v;          // exclusive prefix of block sums
  if (t == 255) rowptr[N] = s[255];
}

__global__ __launch_bounds__(256) void scan_write(const int* __restrict__ cnt,
                                                  const int* __restrict__ boff,
                                                  int* __restrict__ rowptr,
                                                  float* __restrict__ dinv,
                                                  int N, int chunk) {
  __shared__ int s[256];
  int t = threadIdx.x, b = blockIdx.x;
  int i = b * chunk + t;
  int c = (t < chunk && i < N) ? cnt[i] : 0;
  s[t] = c;
  __syncthreads();
#pragma unroll
  for (int off = 1; off < 256; off <<= 1) {
    int u = (t >= off) ? s[t - off] : 0;
    __syncthreads();
    s[t] += u;
    __syncthreads();
  }
  if (t < chunk && i < N) {
    rowptr[i] = boff[b] + s[t] - c;          // exclusive within block + block offset
    dinv[i] = rsqrtf((float)c + 1.0f);       // +1 self-loop; deg >= 1 always
  }
}

__global__ void fill_csr(const int* __restrict__ src, const int* __restrict__ dst,
                         const float* __restrict__ dinv, int* __restrict__ cursor,
                         const int* __restrict__ rowptr, int* __restrict__ csr_src,
                         float* __restrict__ csr_w, int E) {
  int e = blockIdx.x * blockDim.x + threadIdx.x;
  if (e >= E) return;
  int d = dst[e], s = src[e];
  int pos = atomicAdd(&cursor[d], 1);
  int idx = rowptr[d] + pos;
  csr_src[idx] = s;
  csr_w[idx] = dinv[s] * dinv[d];
}

// ---------------- dense transform: C[N,128] = A[N,128] @ W[128,128] ----------------
// 32 rows/block, 256 threads, thread computes 4x4 register tile.
// W staged in two 64-row k-halves (32KB) + A tile (16KB) -> 48KB LDS.

__global__ __launch_bounds__(256) void gemm_x128(const float* __restrict__ A,
                                                 const float* __restrict__ W,
                                                 float* __restrict__ C, int N) {
  __shared__ float Ws[64 * 128];   // 32KB, current k-half
  __shared__ float As[32 * 128];   // 16KB
  const float4* A4 = (const float4*)A;
  const float4* W4 = (const float4*)W;
  float4* Ws4 = (float4*)Ws;
  float4* As4 = (float4*)As;
  int row0 = blockIdx.x * 32;
  // stage A tile (1024 float4)
#pragma unroll
  for (int i = 0; i < 4; ++i) {
    int idx = threadIdx.x + 256 * i;
    int r = idx >> 5, k4 = idx & 31;
    int grow = row0 + r;
    float4 v = make_float4(0.f, 0.f, 0.f, 0.f);
    if (grow < N) v = A4[(size_t)grow * 32 + k4];
    As4[idx] = v;
  }
  int cg = threadIdx.x & 31;   // col group (4 cols)
  int rg = threadIdx.x >> 5;   // row group (4 rows)
  int r0 = rg * 4;
  float acc[4][4] = {};
  for (int half = 0; half < 2; ++half) {
    __syncthreads();
    // stage 64 rows of W (2048 float4)
#pragma unroll
    for (int i = 0; i < 8; ++i) {
      int idx = threadIdx.x + 256 * i;
      Ws4[idx] = W4[half * 2048 + idx];
    }
    __syncthreads();
#pragma unroll
    for (int k4 = 0; k4 < 16; ++k4) {
      float4 a[4], w[4];
#pragma unroll
      for (int i = 0; i < 4; ++i) a[i] = As4[(r0 + i) * 32 + half * 16 + k4];
#pragma unroll
      for (int j = 0; j < 4; ++j) w[j] = Ws4[(k4 * 4 + j) * 32 + cg];
#pragma unroll
      for (int i = 0; i < 4; ++i) {
        acc[i][0] += a[i].x * w[0].x + a[i].y * w[1].x + a[i].z * w[2].x + a[i].w * w[3].x;
        acc[i][1] += a[i].x * w[0].y + a[i].y * w[1].y + a[i].z * w[2].y + a[i].w * w[3].y;
        acc[i][2] += a[i].x * w[0].z + a[i].y * w[1].z + a[i].z * w[2].z + a[i].w * w[3].z;
        acc[i][3] += a[i].x * w[0].w + a[i].y * w[1].w + a[i].z * w[2].w + a[i].w * w[3].w;
      }
    }
  }
  float4* C4 = (float4*)C;
#pragma unroll
  for (int i = 0; i < 4; ++i) {
    int grow = row0 + r0 + i;
    if (grow < N)
      C4[(size_t)grow * 32 + cg] = make_float4(acc[i][0], acc[i][1], acc[i][2], acc[i][3]);
  }
}

// ---------------- aggregation: out = S*H + b  (gather-CSR, wave per dst node) ----------------
// Edge (src,w) metadata loaded one-per-lane per 64-edge chunk, broadcast via __shfl;
// inner loop is 4 independent H-row gathers in flight. Accumulation order identical
// to sequential CSR order (numerics unchanged vs previous round).

__global__ __launch_bounds__(256) void agg_csr(const float* __restrict__ H,
                                               const int* __restrict__ csr_src,
                                               const float* __restrict__ csr_w,
                                               const int* __restrict__ rowptr,
                                               const float* __restrict__ dinv,
                                               const float* __restrict__ b,
                                               float* __restrict__ out, int N) {
  int node = blockIdx.x * 4 + (threadIdx.x >> 6);
  if (node >= N) return;
  int lane = threadIdx.x & 63;
  int beg = rowptr[node];
  int deg = rowptr[node + 1] - beg;
  float di = dinv[node];
  float sw = di * di;  // self-loop norm
  const float2* H2 = (const float2*)H;
  float2 h0 = H2[(size_t)node * 64 + lane];
  float ax = h0.x * sw, ay = h0.y * sw;
  for (int base = 0; base < deg; base += 64) {
    int m = deg - base; if (m > 64) m = 64;
    int smy = 0; float wmy = 0.f;
    if (lane < m) {
      smy = csr_src[beg + base + lane];
      wmy = csr_w[beg + base + lane];
    }
    int j = 0;
    for (; j + 4 <= m; j += 4) {
      int s0 = __shfl(smy, j), s1 = __shfl(smy, j + 1);
      int s2 = __shfl(smy, j + 2), s3 = __shfl(smy, j + 3);
      float w0 = __shfl(wmy, j), w1 = __shfl(wmy, j + 1);
      float w2 = __shfl(wmy, j + 2), w3 = __shfl(wmy, j + 3);
      float2 v0 = H2[(size_t)s0 * 64 + lane];
      float2 v1 = H2[(size_t)s1 * 64 + lane];
      float2 v2 = H2[(size_t)s2 * 64 + lane];
      float2 v3 = H2[(size_t)s3 * 64 + lane];
      ax += v0.x * w0; ay += v0.y * w0;
      ax += v1.x * w1; ay += v1.y * w1;
      ax += v2.x * w2; ay += v2.y * w2;
      ax += v3.x * w3; ay += v3.y * w3;
    }
    for (; j < m; ++j) {
      int s0 = __shfl(smy, j);
      float w0 = __shfl(wmy, j);
      float2 v0 = H2[(size_t)s0 * 64 + lane];
      ax += v0.x * w0; ay += v0.y * w0;
    }
  }
  float2 bb = ((const float2*)b)[lane];
  ((float2*)out)[(size_t)node * 64 + lane] = make_float2(ax + bb.x, ay + bb.y);
}

// ---------------- head: fold Wp1@Wp2, then per-node 128->16 + log_softmax ----------------

__global__ __launch_bounds__(256) void fuse_w(const float* __restrict__ Wp1,
                                              const float* __restrict__ bp1,
                                              const float* __restrict__ Wp2,
                                              const float* __restrict__ bp2,
                                              float* __restrict__ Wf, float* __restrict__ bf) {
  int tid = threadIdx.x;
  for (int o = tid; o < 2048; o += 256) {
    int r = o >> 4, j = o & 15;
    float s = 0.f;
    for (int k = 0; k < 128; ++k) s += Wp1[r * 128 + k] * Wp2[k * 16 + j];
    Wf[o] = s;
  }
  if (tid < 16) {
    float s = bp2[tid];
    for (int k = 0; k < 128; ++k) s += bp1[k] * Wp2[k * 16 + tid];
    bf[tid] = s;
  }
}

__global__ __launch_bounds__(256) void proj_kernel(const float* __restrict__ emb,
                                                   const float* __restrict__ Wf,
                                                   const float* __restrict__ bf,
                                                   float* __restrict__ out, int N) {
  __shared__ float Ws[2048];
  __shared__ float bfs[16];
  for (int i = threadIdx.x; i < 2048; i += 256) Ws[i] = Wf[i];
  if (threadIdx.x < 16) bfs[threadIdx.x] = bf[threadIdx.x];
  __syncthreads();
  int node = blockIdx.x * 4 + (threadIdx.x >> 6);
  if (node >= N) return;
  int lane = threadIdx.x & 63;
  int j = lane & 15, g = lane >> 4;   // lane owns output j, k-range [32g, 32g+32)
  const float* er = emb + (size_t)node * 128 + g * 32;
  float p = 0.f;
#pragma unroll
  for (int k = 0; k < 32; ++k) p += er[k] * Ws[(g * 32 + k) * 16 + j];
  p += __shfl_xor(p, 16);
  p += __shfl_xor(p, 32);
  p += bfs[j];
  float mx = p;
#pragma unroll
  for (int o = 1; o < 16; o <<= 1) mx = fmaxf(mx, __shfl_xor(mx, o));
  float ex = expf(p - mx);
  float sm = ex;
#pragma unroll
  for (int o = 1; o < 16; o <<= 1) sm += __shfl_xor(sm, o);
  float res = p - mx - logf(sm);
  if (lane < 16) out[(size_t)node * 16 + j] = res;
}

// ---------------- launch ----------------

extern "C" void kernel_launch(void* const* d_in, const int* in_sizes, int n_in,
                              void* d_out, int out_size, void* d_ws, size_t ws_size,
                              hipStream_t stream) {
  const float* x   = (const float*)d_in[0];
  const int*   ei  = (const int*)d_in[1];
  const float* W1  = (const float*)d_in[2];
  const float* b1  = (const float*)d_in[3];
  const float* W2  = (const float*)d_in[4];
  const float* b2  = (const float*)d_in[5];
  const float* W3  = (const float*)d_in[6];
  const float* b3  = (const float*)d_in[7];
  const float* Wp1 = (const float*)d_in[8];
  const float* bp1 = (const float*)d_in[9];
  const float* Wp2 = (const float*)d_in[10];
  const float* bp2 = (const float*)d_in[11];

  const int N = in_sizes[0] / 128;
  const int E = in_sizes[1] / 2;
  const int* src = ei;       // edge_index[0]
  const int* dst = ei + E;   // edge_index[1]

  float* out    = (float*)d_out;
  float* emb    = out;                       // [N,128] embedding slice, also ping buffer
  float* scores = out + (size_t)N * 128;     // [N,16]

  char* w = (char*)d_ws;
  auto alloc = [&](size_t bytes) {
    char* p = w;
    w += (bytes + 255) & ~(size_t)255;
    return p;
  };
  int*   cntcur  = (int*)alloc((size_t)2 * N * 4);  // cnt | cursor, one zero pass
  int*   cnt     = cntcur;
  int*   cursor  = cntcur + N;
  int*   rowptr  = (int*)alloc(((size_t)N + 1) * 4);
  float* dinv    = (float*)alloc((size_t)N * 4);
  int*   csr_src = (int*)alloc((size_t)E * 4);
  float* csr_w   = (float*)alloc((size_t)E * 4);
  float* H       = (float*)alloc((size_t)N * 128 * 4);
  float* Wf      = (float*)alloc(2048 * 4);
  float* bf      = (float*)alloc(16 * 4);
  int*   bsum    = (int*)alloc(256 * 4);
  int*   boff    = (int*)alloc(256 * 4);

  int gE = (E + 255) / 256;
  int chunk = (N + 255) / 256;   // <= 256 required (N <= 65536)

  zero_ints<<<(2 * N + 255) / 256, 256, 0, stream>>>(cntcur, 2 * N);
  count_dst<<<gE, 256, 0, stream>>>(dst, cnt, E);
  scan_blocksums<<<256, 256, 0, stream>>>(cnt, bsum, N, chunk);
  scan_offsets<<<1, 256, 0, stream>>>(bsum, boff, rowptr, N);
  scan_write<<<256, 256, 0, stream>>>(cnt, boff, rowptr, dinv, N, chunk);
  fill_csr<<<gE, 256, 0, stream>>>(src, dst, dinv, cursor, rowptr, csr_src, csr_w, E);
  fuse_w<<<1, 256, 0, stream>>>(Wp1, bp1, Wp2, bp2, Wf, bf);

  int gemm_grid = (N + 31) / 32;
  int node_grid = (N + 3) / 4;
  gemm_x128<<<gemm_grid, 256, 0, stream>>>(x, W1, H, N);
  agg_csr<<<node_grid, 256, 0, stream>>>(H, csr_src, csr_w, rowptr, dinv, b1, emb, N);
  gemm_x128<<<gemm_grid, 256, 0, stream>>>(emb, W2, H, N);
  agg_csr<<<node_grid, 256, 0, stream>>>(H, csr_src, csr_w, rowptr, dinv, b2, emb, N);
  gemm_x128<<<gemm_grid, 256, 0, stream>>>(emb, W3, H, N);
  agg_csr<<<node_grid, 256, 0, stream>>>(H, csr_src, csr_w, rowptr, dinv, b3, emb, N);
  proj_kernel<<<node_grid, 256, 0, stream>>>(emb, Wf, bf, scores, N);
}

// Round 12
// 389.164 us; speedup vs baseline: 1.7049x; 1.4827x over previous
//
#include <hip/hip_runtime.h>
#include <math.h>

typedef __attribute__((ext_vector_type(8))) short short8v;  // 8 bf16 (4 VGPRs)
typedef __attribute__((ext_vector_type(4))) float f32x4;    // 4 fp32 acc

static __device__ __forceinline__ ushort f2bf(float f) {
  union { float f; unsigned u; } v; v.f = f;
  unsigned r = v.u + 0x7FFF + ((v.u >> 16) & 1);  // RNE
  return (ushort)(r >> 16);
}
static __device__ __forceinline__ float bflo(unsigned p) {  // low bf16 of packed pair
  union { unsigned u; float f; } v; v.u = p << 16; return v.f;
}
static __device__ __forceinline__ float bfhi(unsigned p) {  // high bf16
  union { unsigned u; float f; } v; v.u = p & 0xFFFF0000u; return v.f;
}

// ---------------- CSR build ----------------

__global__ void zero_ints(int* __restrict__ a, int n) {
  int i = blockIdx.x * blockDim.x + threadIdx.x;
  if (i < n) a[i] = 0;
}

__global__ void count_dst(const int* __restrict__ dst, int* __restrict__ cnt, int E) {
  int e = blockIdx.x * blockDim.x + threadIdx.x;
  if (e < E) atomicAdd(&cnt[dst[e]], 1);
}

// ---- 3-phase multi-block scan; requires ceil(N/256) <= 256 (N <= 65536) ----

__global__ __launch_bounds__(256) void scan_blocksums(const int* __restrict__ cnt,
                                                      int* __restrict__ bsum,
                                                      int N, int chunk) {
  __shared__ int red[256];
  int t = threadIdx.x, b = blockIdx.x;
  int i = b * chunk + t;
  red[t] = (t < chunk && i < N) ? cnt[i] : 0;
  __syncthreads();
#pragma unroll
  for (int off = 128; off > 0; off >>= 1) {
    if (t < off) red[t] += red[t + off];
    __syncthreads();
  }
  if (t == 0) bsum[b] = red[0];
}

__global__ __launch_bounds__(256) void scan_offsets(const int* __restrict__ bsum,
                                                    int* __restrict__ boff,
                                                    int* __restrict__ rowptr, int N) {
  __shared__ int s[256];
  int t = threadIdx.x;
  int v = bsum[t];
  s[t] = v;
  __syncthreads();
#pragma unroll
  for (int off = 1; off < 256; off <<= 1) {
    int u = (t >= off) ? s[t - off] : 0;
    __syncthreads();
    s[t] += u;
    __syncthreads();
  }
  boff[t] = s[t] - v;
  if (t == 255) rowptr[N] = s[255];
}

__global__ __launch_bounds__(256) void scan_write(const int* __restrict__ cnt,
                                                  const int* __restrict__ boff,
                                                  int* __restrict__ rowptr,
                                                  float* __restrict__ dinv,
                                                  int N, int chunk) {
  __shared__ int s[256];
  int t = threadIdx.x, b = blockIdx.x;
  int i = b * chunk + t;
  int c = (t < chunk && i < N) ? cnt[i] : 0;
  s[t] = c;
  __syncthreads();
#pragma unroll
  for (int off = 1; off < 256; off <<= 1) {
    int u = (t >= off) ? s[t - off] : 0;
    __syncthreads();
    s[t] += u;
    __syncthreads();
  }
  if (t < chunk && i < N) {
    rowptr[i] = boff[b] + s[t] - c;
    dinv[i] = rsqrtf((float)c + 1.0f);  // +1 self-loop
  }
}

__global__ void fill_csr(const int* __restrict__ src, const int* __restrict__ dst,
                         const float* __restrict__ dinv, int* __restrict__ cursor,
                         const int* __restrict__ rowptr, int* __restrict__ csr_src,
                         float* __restrict__ csr_w, int E) {
  int e = blockIdx.x * blockDim.x + threadIdx.x;
  if (e >= E) return;
  int d = dst[e], s = src[e];
  int pos = atomicAdd(&cursor[d], 1);
  int idx = rowptr[d] + pos;
  csr_src[idx] = s;
  csr_w[idx] = dinv[s] * dinv[d];
}

// ---------------- W -> bf16 B-fragment layout: Wb[kb*1024 + n*8 + j] = W[kb*8+j][n] ----------------

__global__ __launch_bounds__(256) void transform_w(const float* __restrict__ W1,
                                                   const float* __restrict__ W2,
                                                   const float* __restrict__ W3,
                                                   ushort* __restrict__ Wb1,
                                                   ushort* __restrict__ Wb2,
                                                   ushort* __restrict__ Wb3) {
  const float* W = (blockIdx.x == 0) ? W1 : (blockIdx.x == 1) ? W2 : W3;
  ushort* Wb = (blockIdx.x == 0) ? Wb1 : (blockIdx.x == 1) ? Wb2 : Wb3;
  for (int i = threadIdx.x; i < 16384; i += 256) {
    int kb = i >> 10, rem = i & 1023, n = rem >> 3, j = rem & 7;
    Wb[i] = f2bf(W[(kb * 8 + j) * 128 + n]);
  }
}

// ---------------- MFMA GEMM: Hb[N,128](bf16) = A[N,128] @ W[128,128] ----------------
// 256 thr = 4 waves, 64 rows/block. A staged to LDS bf16 [64][136] (pad kills bank conflicts).
// Wb (B-frag layout) staged 32KB to LDS. Per wave: 16 rows, 8 col-tiles, 4 K-steps of
// mfma_f32_16x16x32_bf16. Layouts: A/B lane l -> row/col l&15, k=(l>>4)*8+j;
// C/D col=lane&15, row=(lane>>4)*4+reg (m89-verified).

template<bool AF32>
__global__ __launch_bounds__(256) void gemm_mfma(const void* __restrict__ Av,
                                                 const ushort* __restrict__ Wb,
                                                 ushort* __restrict__ Hb, int N) {
  __shared__ __align__(16) ushort As[64 * 136];
  __shared__ __align__(16) ushort Ws[16384];
  int tid = threadIdx.x;
  int row0 = blockIdx.x * 64;
  {  // stage W: 32KB = 2048 int4
    const int4* s = (const int4*)Wb;
    int4* d = (int4*)Ws;
#pragma unroll
    for (int i = 0; i < 8; ++i) d[tid + 256 * i] = s[tid + 256 * i];
  }
  if (AF32) {  // stage A from f32, convert
    const float4* A4 = (const float4*)Av;
#pragma unroll
    for (int i = 0; i < 8; ++i) {
      int idx = tid + 256 * i;          // 2048 float4
      int r = idx >> 5, k4 = idx & 31;
      int grow = row0 + r;
      float4 v = make_float4(0.f, 0.f, 0.f, 0.f);
      if (grow < N) v = A4[(size_t)grow * 32 + k4];
      ushort4 u;
      u.x = f2bf(v.x); u.y = f2bf(v.y); u.z = f2bf(v.z); u.w = f2bf(v.w);
      *(ushort4*)&As[r * 136 + k4 * 4] = u;
    }
  } else {  // stage A from bf16
    const int4* A8 = (const int4*)Av;
#pragma unroll
    for (int i = 0; i < 4; ++i) {
      int idx = tid + 256 * i;          // 1024 chunks of 8 bf16
      int r = idx >> 4, k8 = idx & 15;
      int grow = row0 + r;
      int4 v = make_int4(0, 0, 0, 0);
      if (grow < N) v = A8[(size_t)grow * 16 + k8];
      *(int4*)&As[r * 136 + k8 * 8] = v;
    }
  }
  __syncthreads();
  int wave = tid >> 6, lane = tid & 63;
  int lrow = lane & 15, kb = lane >> 4;  // kb in 0..3
  short8v a[4];
#pragma unroll
  for (int s = 0; s < 4; ++s)
    a[s] = *(const short8v*)&As[(wave * 16 + lrow) * 136 + s * 32 + kb * 8];
#pragma unroll
  for (int c = 0; c < 8; ++c) {
    f32x4 acc = {0.f, 0.f, 0.f, 0.f};
#pragma unroll
    for (int s = 0; s < 4; ++s) {
      short8v b = *(const short8v*)&Ws[(4 * s + kb) * 1024 + (c * 16 + lrow) * 8];
      acc = __builtin_amdgcn_mfma_f32_16x16x32_bf16(a[s], b, acc, 0, 0, 0);
    }
    int col = c * 16 + lrow;
    int r = row0 + wave * 16 + kb * 4;
#pragma unroll
    for (int j = 0; j < 4; ++j)
      if (r + j < N) Hb[(size_t)(r + j) * 128 + col] = f2bf(acc[j]);
  }
}

// ---------------- aggregation: out = S*H + b (gather bf16 H, f32 accumulate) ----------------
// Wave per dst node; edge meta one-per-lane per 64-edge chunk, __shfl broadcast;
// 4 independent gathers in flight. outf (f32, final layer) / outb (bf16) nullable.

__global__ __launch_bounds__(256) void agg_csr(const ushort* __restrict__ Hb,
                                               const int* __restrict__ csr_src,
                                               const float* __restrict__ csr_w,
                                               const int* __restrict__ rowptr,
                                               const float* __restrict__ dinv,
                                               const float* __restrict__ b,
                                               float* __restrict__ outf,
                                               ushort* __restrict__ outb, int N) {
  int node = blockIdx.x * 4 + (threadIdx.x >> 6);
  if (node >= N) return;
  int lane = threadIdx.x & 63;
  int beg = rowptr[node];
  int deg = rowptr[node + 1] - beg;
  float di = dinv[node];
  float sw = di * di;  // self-loop norm
  const unsigned* H2 = (const unsigned*)Hb;  // 2 bf16 per u32
  unsigned hp = H2[(size_t)node * 64 + lane];
  float ax = bflo(hp) * sw, ay = bfhi(hp) * sw;
  for (int base = 0; base < deg; base += 64) {
    int m = deg - base; if (m > 64) m = 64;
    int smy = 0; float wmy = 0.f;
    if (lane < m) {
      smy = csr_src[beg + base + lane];
      wmy = csr_w[beg + base + lane];
    }
    int j = 0;
    for (; j + 4 <= m; j += 4) {
      int s0 = __shfl(smy, j), s1 = __shfl(smy, j + 1);
      int s2 = __shfl(smy, j + 2), s3 = __shfl(smy, j + 3);
      float w0 = __shfl(wmy, j), w1 = __shfl(wmy, j + 1);
      float w2 = __shfl(wmy, j + 2), w3 = __shfl(wmy, j + 3);
      unsigned p0 = H2[(size_t)s0 * 64 + lane];
      unsigned p1 = H2[(size_t)s1 * 64 + lane];
      unsigned p2 = H2[(size_t)s2 * 64 + lane];
      unsigned p3 = H2[(size_t)s3 * 64 + lane];
      ax += bflo(p0) * w0; ay += bfhi(p0) * w0;
      ax += bflo(p1) * w1; ay += bfhi(p1) * w1;
      ax += bflo(p2) * w2; ay += bfhi(p2) * w2;
      ax += bflo(p3) * w3; ay += bfhi(p3) * w3;
    }
    for (; j < m; ++j) {
      int s0 = __shfl(smy, j);
      float w0 = __shfl(wmy, j);
      unsigned p0 = H2[(size_t)s0 * 64 + lane];
      ax += bflo(p0) * w0; ay += bfhi(p0) * w0;
    }
  }
  float2 bb = ((const float2*)b)[lane];
  float rx = ax + bb.x, ry = ay + bb.y;
  if (outf) ((float2*)outf)[(size_t)node * 64 + lane] = make_float2(rx, ry);
  if (outb) {
    ushort2 u; u.x = f2bf(rx); u.y = f2bf(ry);
    *(ushort2*)&outb[(size_t)node * 128 + 2 * lane] = u;
  }
}

// ---------------- head: fold Wp1@Wp2, then per-node 128->16 + log_softmax ----------------

__global__ __launch_bounds__(256) void fuse_w(const float* __restrict__ Wp1,
                                              const float* __restrict__ bp1,
                                              const float* __restrict__ Wp2,
                                              const float* __restrict__ bp2,
                                              float* __restrict__ Wf, float* __restrict__ bf) {
  int tid = threadIdx.x;
  for (int o = tid; o < 2048; o += 256) {
    int r = o >> 4, j = o & 15;
    float s = 0.f;
    for (int k = 0; k < 128; ++k) s += Wp1[r * 128 + k] * Wp2[k * 16 + j];
    Wf[o] = s;
  }
  if (tid < 16) {
    float s = bp2[tid];
    for (int k = 0; k < 128; ++k) s += bp1[k] * Wp2[k * 16 + tid];
    bf[tid] = s;
  }
}

__global__ __launch_bounds__(256) void proj_kernel(const float* __restrict__ emb,
                                                   const float* __restrict__ Wf,
                                                   const float* __restrict__ bf,
                                                   float* __restrict__ out, int N) {
  __shared__ float Ws[2048];
  __shared__ float bfs[16];
  for (int i = threadIdx.x; i < 2048; i += 256) Ws[i] = Wf[i];
  if (threadIdx.x < 16) bfs[threadIdx.x] = bf[threadIdx.x];
  __syncthreads();
  int node = blockIdx.x * 4 + (threadIdx.x >> 6);
  if (node >= N) return;
  int lane = threadIdx.x & 63;
  int j = lane & 15, g = lane >> 4;
  const float* er = emb + (size_t)node * 128 + g * 32;
  float p = 0.f;
#pragma unroll
  for (int k = 0; k < 32; ++k) p += er[k] * Ws[(g * 32 + k) * 16 + j];
  p += __shfl_xor(p, 16);
  p += __shfl_xor(p, 32);
  p += bfs[j];
  float mx = p;
#pragma unroll
  for (int o = 1; o < 16; o <<= 1) mx = fmaxf(mx, __shfl_xor(mx, o));
  float ex = expf(p - mx);
  float sm = ex;
#pragma unroll
  for (int o = 1; o < 16; o <<= 1) sm += __shfl_xor(sm, o);
  float res = p - mx - logf(sm);
  if (lane < 16) out[(size_t)node * 16 + j] = res;
}

// ---------------- launch ----------------

extern "C" void kernel_launch(void* const* d_in, const int* in_sizes, int n_in,
                              void* d_out, int out_size, void* d_ws, size_t ws_size,
                              hipStream_t stream) {
  const float* x   = (const float*)d_in[0];
  const int*   ei  = (const int*)d_in[1];
  const float* W1  = (const float*)d_in[2];
  const float* b1  = (const float*)d_in[3];
  const float* W2  = (const float*)d_in[4];
  const float* b2  = (const float*)d_in[5];
  const float* W3  = (const float*)d_in[6];
  const float* b3  = (const float*)d_in[7];
  const float* Wp1 = (const float*)d_in[8];
  const float* bp1 = (const float*)d_in[9];
  const float* Wp2 = (const float*)d_in[10];
  const float* bp2 = (const float*)d_in[11];

  const int N = in_sizes[0] / 128;
  const int E = in_sizes[1] / 2;
  const int* src = ei;       // edge_index[0]
  const int* dst = ei + E;   // edge_index[1]

  float* out    = (float*)d_out;
  float* emb    = out;                    // [N,128] final embedding
  float* scores = out + (size_t)N * 128;  // [N,16]

  char* w = (char*)d_ws;
  auto alloc = [&](size_t bytes) {
    char* p = w;
    w += (bytes + 255) & ~(size_t)255;
    return p;
  };
  int*    cntcur  = (int*)alloc((size_t)2 * N * 4);  // cnt | cursor
  int*    cnt     = cntcur;
  int*    cursor  = cntcur + N;
  int*    rowptr  = (int*)alloc(((size_t)N + 1) * 4);
  float*  dinv    = (float*)alloc((size_t)N * 4);
  int*    csr_src = (int*)alloc((size_t)E * 4);
  float*  csr_w   = (float*)alloc((size_t)E * 4);
  ushort* Hb      = (ushort*)alloc((size_t)N * 128 * 2);  // gemm out (bf16)
  ushort* Ab      = (ushort*)alloc((size_t)N * 128 * 2);  // agg out (bf16)
  ushort* Wb1     = (ushort*)alloc(16384 * 2);
  ushort* Wb2     = (ushort*)alloc(16384 * 2);
  ushort* Wb3     = (ushort*)alloc(16384 * 2);
  float*  Wf      = (float*)alloc(2048 * 4);
  float*  bf      = (float*)alloc(16 * 4);
  int*    bsum    = (int*)alloc(256 * 4);
  int*    boff    = (int*)alloc(256 * 4);

  int gE = (E + 255) / 256;
  int chunk = (N + 255) / 256;  // <= 256 required (N <= 65536)

  zero_ints<<<(2 * N + 255) / 256, 256, 0, stream>>>(cntcur, 2 * N);
  count_dst<<<gE, 256, 0, stream>>>(dst, cnt, E);
  scan_blocksums<<<256, 256, 0, stream>>>(cnt, bsum, N, chunk);
  scan_offsets<<<1, 256, 0, stream>>>(bsum, boff, rowptr, N);
  scan_write<<<256, 256, 0, stream>>>(cnt, boff, rowptr, dinv, N, chunk);
  fill_csr<<<gE, 256, 0, stream>>>(src, dst, dinv, cursor, rowptr, csr_src, csr_w, E);
  transform_w<<<3, 256, 0, stream>>>(W1, W2, W3, Wb1, Wb2, Wb3);
  fuse_w<<<1, 256, 0, stream>>>(Wp1, bp1, Wp2, bp2, Wf, bf);

  int gemm_grid = (N + 63) / 64;
  int node_grid = (N + 3) / 4;
  gemm_mfma<true><<<gemm_grid, 256, 0, stream>>>(x, Wb1, Hb, N);
  agg_csr<<<node_grid, 256, 0, stream>>>(Hb, csr_src, csr_w, rowptr, dinv, b1, nullptr, Ab, N);
  gemm_mfma<false><<<gemm_grid, 256, 0, stream>>>(Ab, Wb2, Hb, N);
  agg_csr<<<node_grid, 256, 0, stream>>>(Hb, csr_src, csr_w, rowptr, dinv, b2, nullptr, Ab, N);
  gemm_mfma<false><<<gemm_grid, 256, 0, stream>>>(Ab, Wb3, Hb, N);
  agg_csr<<<node_grid, 256, 0, stream>>>(Hb, csr_src, csr_w, rowptr, dinv, b3, emb, nullptr, N);
  proj_kernel<<<node_grid, 256, 0, stream>>>(emb, Wf, bf, scores, N);
}

// Round 13
// 382.059 us; speedup vs baseline: 1.7366x; 1.0186x over previous
//
#include <hip/hip_runtime.h>
#include <math.h>

typedef __attribute__((ext_vector_type(8))) short short8v;  // 8 bf16 (4 VGPRs)
typedef __attribute__((ext_vector_type(4))) float f32x4;    // 4 fp32 acc

static __device__ __forceinline__ ushort f2bf(float f) {
  union { float f; unsigned u; } v; v.f = f;
  unsigned r = v.u + 0x7FFF + ((v.u >> 16) & 1);  // RNE
  return (ushort)(r >> 16);
}
static __device__ __forceinline__ float bflo(unsigned p) {  // low bf16 of packed pair
  union { unsigned u; float f; } v; v.u = p << 16; return v.f;
}
static __device__ __forceinline__ float bfhi(unsigned p) {  // high bf16
  union { unsigned u; float f; } v; v.u = p & 0xFFFF0000u; return v.f;
}

// ---------------- CSR build ----------------

__global__ void zero_ints(int* __restrict__ a, int n) {
  int i = blockIdx.x * blockDim.x + threadIdx.x;
  if (i < n) a[i] = 0;
}

__global__ void count_dst(const int* __restrict__ dst, int* __restrict__ cnt, int E) {
  int e = blockIdx.x * blockDim.x + threadIdx.x;
  if (e < E) atomicAdd(&cnt[dst[e]], 1);
}

// ---- 3-phase multi-block scan; requires ceil(N/256) <= 256 (N <= 65536) ----

__global__ __launch_bounds__(256) void scan_blocksums(const int* __restrict__ cnt,
                                                      int* __restrict__ bsum,
                                                      int N, int chunk) {
  __shared__ int red[256];
  int t = threadIdx.x, b = blockIdx.x;
  int i = b * chunk + t;
  red[t] = (t < chunk && i < N) ? cnt[i] : 0;
  __syncthreads();
#pragma unroll
  for (int off = 128; off > 0; off >>= 1) {
    if (t < off) red[t] += red[t + off];
    __syncthreads();
  }
  if (t == 0) bsum[b] = red[0];
}

__global__ __launch_bounds__(256) void scan_offsets(const int* __restrict__ bsum,
                                                    int* __restrict__ boff,
                                                    int* __restrict__ rowptr, int N) {
  __shared__ int s[256];
  int t = threadIdx.x;
  int v = bsum[t];
  s[t] = v;
  __syncthreads();
#pragma unroll
  for (int off = 1; off < 256; off <<= 1) {
    int u = (t >= off) ? s[t - off] : 0;
    __syncthreads();
    s[t] += u;
    __syncthreads();
  }
  boff[t] = s[t] - v;
  if (t == 255) rowptr[N] = s[255];
}

// writes rowptr, dinv, and cursor (= rowptr copy, so fill_csr needs no rowptr read)
__global__ __launch_bounds__(256) void scan_write(const int* __restrict__ cnt,
                                                  const int* __restrict__ boff,
                                                  int* __restrict__ rowptr,
                                                  int* __restrict__ cursor,
                                                  float* __restrict__ dinv,
                                                  int N, int chunk) {
  __shared__ int s[256];
  int t = threadIdx.x, b = blockIdx.x;
  int i = b * chunk + t;
  int c = (t < chunk && i < N) ? cnt[i] : 0;
  s[t] = c;
  __syncthreads();
#pragma unroll
  for (int off = 1; off < 256; off <<= 1) {
    int u = (t >= off) ? s[t - off] : 0;
    __syncthreads();
    s[t] += u;
    __syncthreads();
  }
  if (t < chunk && i < N) {
    int rp = boff[b] + s[t] - c;
    rowptr[i] = rp;
    cursor[i] = rp;
    dinv[i] = rsqrtf((float)c + 1.0f);  // +1 self-loop
  }
}

// packed CSR entry: .x = src node, .y = f32 bits of norm weight.
// One 8B scattered write per edge (vs 2x4B) -> ~halves write amplification.
__global__ void fill_csr(const int* __restrict__ src, const int* __restrict__ dst,
                         const float* __restrict__ dinv, int* __restrict__ cursor,
                         int2* __restrict__ csr, int E) {
  int e = blockIdx.x * blockDim.x + threadIdx.x;
  if (e >= E) return;
  int d = dst[e], s = src[e];
  int idx = atomicAdd(&cursor[d], 1);  // cursor pre-seeded with rowptr
  float w = dinv[s] * dinv[d];
  csr[idx] = make_int2(s, __float_as_int(w));
}

// ---------------- W -> bf16 B-fragment layout: Wb[kb*1024 + n*8 + j] = W[kb*8+j][n] ----------------

__global__ __launch_bounds__(256) void transform_w(const float* __restrict__ W1,
                                                   const float* __restrict__ W2,
                                                   const float* __restrict__ W3,
                                                   ushort* __restrict__ Wb1,
                                                   ushort* __restrict__ Wb2,
                                                   ushort* __restrict__ Wb3) {
  const float* W = (blockIdx.x == 0) ? W1 : (blockIdx.x == 1) ? W2 : W3;
  ushort* Wb = (blockIdx.x == 0) ? Wb1 : (blockIdx.x == 1) ? Wb2 : Wb3;
  for (int i = threadIdx.x; i < 16384; i += 256) {
    int kb = i >> 10, rem = i & 1023, n = rem >> 3, j = rem & 7;
    Wb[i] = f2bf(W[(kb * 8 + j) * 128 + n]);
  }
}

// ---------------- MFMA GEMM: Hb[N,128](bf16) = A[N,128] @ W[128,128] ----------------
// 256 thr = 4 waves, 64 rows/block. A staged to LDS bf16 [64][136] (pad kills bank conflicts).
// Wb (B-frag layout) staged 32KB to LDS. Per wave: 16 rows, 8 col-tiles, 4 K-steps of
// mfma_f32_16x16x32_bf16. Layouts: A/B lane l -> row/col l&15, k=(l>>4)*8+j;
// C/D col=lane&15, row=(lane>>4)*4+reg (m89-verified).

template<bool AF32>
__global__ __launch_bounds__(256) void gemm_mfma(const void* __restrict__ Av,
                                                 const ushort* __restrict__ Wb,
                                                 ushort* __restrict__ Hb, int N) {
  __shared__ __align__(16) ushort As[64 * 136];
  __shared__ __align__(16) ushort Ws[16384];
  int tid = threadIdx.x;
  int row0 = blockIdx.x * 64;
  {  // stage W: 32KB = 2048 int4
    const int4* s = (const int4*)Wb;
    int4* d = (int4*)Ws;
#pragma unroll
    for (int i = 0; i < 8; ++i) d[tid + 256 * i] = s[tid + 256 * i];
  }
  if (AF32) {  // stage A from f32, convert
    const float4* A4 = (const float4*)Av;
#pragma unroll
    for (int i = 0; i < 8; ++i) {
      int idx = tid + 256 * i;          // 2048 float4
      int r = idx >> 5, k4 = idx & 31;
      int grow = row0 + r;
      float4 v = make_float4(0.f, 0.f, 0.f, 0.f);
      if (grow < N) v = A4[(size_t)grow * 32 + k4];
      ushort4 u;
      u.x = f2bf(v.x); u.y = f2bf(v.y); u.z = f2bf(v.z); u.w = f2bf(v.w);
      *(ushort4*)&As[r * 136 + k4 * 4] = u;
    }
  } else {  // stage A from bf16
    const int4* A8 = (const int4*)Av;
#pragma unroll
    for (int i = 0; i < 4; ++i) {
      int idx = tid + 256 * i;          // 1024 chunks of 8 bf16
      int r = idx >> 4, k8 = idx & 15;
      int grow = row0 + r;
      int4 v = make_int4(0, 0, 0, 0);
      if (grow < N) v = A8[(size_t)grow * 16 + k8];
      *(int4*)&As[r * 136 + k8 * 8] = v;
    }
  }
  __syncthreads();
  int wave = tid >> 6, lane = tid & 63;
  int lrow = lane & 15, kb = lane >> 4;  // kb in 0..3
  short8v a[4];
#pragma unroll
  for (int s = 0; s < 4; ++s)
    a[s] = *(const short8v*)&As[(wave * 16 + lrow) * 136 + s * 32 + kb * 8];
#pragma unroll
  for (int c = 0; c < 8; ++c) {
    f32x4 acc = {0.f, 0.f, 0.f, 0.f};
#pragma unroll
    for (int s = 0; s < 4; ++s) {
      short8v b = *(const short8v*)&Ws[(4 * s + kb) * 1024 + (c * 16 + lrow) * 8];
      acc = __builtin_amdgcn_mfma_f32_16x16x32_bf16(a[s], b, acc, 0, 0, 0);
    }
    int col = c * 16 + lrow;
    int r = row0 + wave * 16 + kb * 4;
#pragma unroll
    for (int j = 0; j < 4; ++j)
      if (r + j < N) Hb[(size_t)(r + j) * 128 + col] = f2bf(acc[j]);
  }
}

// ---------------- aggregation: out = S*H + b (gather bf16 H, f32 accumulate) ----------------
// Wave per dst node; packed (src,w) int2 one-per-lane per 64-edge chunk, __shfl broadcast;
// 4 independent gathers in flight. outf (f32, final layer) / outb (bf16) nullable.

__global__ __launch_bounds__(256) void agg_csr(const ushort* __restrict__ Hb,
                                               const int2* __restrict__ csr,
                                               const int* __restrict__ rowptr,
                                               const float* __restrict__ dinv,
                                               const float* __restrict__ b,
                                               float* __restrict__ outf,
                                               ushort* __restrict__ outb, int N) {
  int node = blockIdx.x * 4 + (threadIdx.x >> 6);
  if (node >= N) return;
  int lane = threadIdx.x & 63;
  int beg = rowptr[node];
  int deg = rowptr[node + 1] - beg;
  float di = dinv[node];
  float sw = di * di;  // self-loop norm
  const unsigned* H2 = (const unsigned*)Hb;  // 2 bf16 per u32
  unsigned hp = H2[(size_t)node * 64 + lane];
  float ax = bflo(hp) * sw, ay = bfhi(hp) * sw;
  for (int base = 0; base < deg; base += 64) {
    int m = deg - base; if (m > 64) m = 64;
    int smy = 0; float wmy = 0.f;
    if (lane < m) {
      int2 c = csr[beg + base + lane];
      smy = c.x;
      wmy = __int_as_float(c.y);
    }
    int j = 0;
    for (; j + 4 <= m; j += 4) {
      int s0 = __shfl(smy, j), s1 = __shfl(smy, j + 1);
      int s2 = __shfl(smy, j + 2), s3 = __shfl(smy, j + 3);
      float w0 = __shfl(wmy, j), w1 = __shfl(wmy, j + 1);
      float w2 = __shfl(wmy, j + 2), w3 = __shfl(wmy, j + 3);
      unsigned p0 = H2[(size_t)s0 * 64 + lane];
      unsigned p1 = H2[(size_t)s1 * 64 + lane];
      unsigned p2 = H2[(size_t)s2 * 64 + lane];
      unsigned p3 = H2[(size_t)s3 * 64 + lane];
      ax += bflo(p0) * w0; ay += bfhi(p0) * w0;
      ax += bflo(p1) * w1; ay += bfhi(p1) * w1;
      ax += bflo(p2) * w2; ay += bfhi(p2) * w2;
      ax += bflo(p3) * w3; ay += bfhi(p3) * w3;
    }
    for (; j < m; ++j) {
      int s0 = __shfl(smy, j);
      float w0 = __shfl(wmy, j);
      unsigned p0 = H2[(size_t)s0 * 64 + lane];
      ax += bflo(p0) * w0; ay += bfhi(p0) * w0;
    }
  }
  float2 bb = ((const float2*)b)[lane];
  float rx = ax + bb.x, ry = ay + bb.y;
  if (outf) ((float2*)outf)[(size_t)node * 64 + lane] = make_float2(rx, ry);
  if (outb) {
    ushort2 u; u.x = f2bf(rx); u.y = f2bf(ry);
    *(ushort2*)&outb[(size_t)node * 128 + 2 * lane] = u;
  }
}

// ---------------- head: fold Wp1@Wp2, then per-node 128->16 + log_softmax ----------------

__global__ __launch_bounds__(256) void fuse_w(const float* __restrict__ Wp1,
                                              const float* __restrict__ bp1,
                                              const float* __restrict__ Wp2,
                                              const float* __restrict__ bp2,
                                              float* __restrict__ Wf, float* __restrict__ bf) {
  int tid = threadIdx.x;
  for (int o = tid; o < 2048; o += 256) {
    int r = o >> 4, j = o & 15;
    float s = 0.f;
    for (int k = 0; k < 128; ++k) s += Wp1[r * 128 + k] * Wp2[k * 16 + j];
    Wf[o] = s;
  }
  if (tid < 16) {
    float s = bp2[tid];
    for (int k = 0; k < 128; ++k) s += bp1[k] * Wp2[k * 16 + tid];
    bf[tid] = s;
  }
}

__global__ __launch_bounds__(256) void proj_kernel(const float* __restrict__ emb,
                                                   const float* __restrict__ Wf,
                                                   const float* __restrict__ bf,
                                                   float* __restrict__ out, int N) {
  __shared__ float Ws[2048];
  __shared__ float bfs[16];
  for (int i = threadIdx.x; i < 2048; i += 256) Ws[i] = Wf[i];
  if (threadIdx.x < 16) bfs[threadIdx.x] = bf[threadIdx.x];
  __syncthreads();
  int node = blockIdx.x * 4 + (threadIdx.x >> 6);
  if (node >= N) return;
  int lane = threadIdx.x & 63;
  int j = lane & 15, g = lane >> 4;
  const float* er = emb + (size_t)node * 128 + g * 32;
  float p = 0.f;
#pragma unroll
  for (int k = 0; k < 32; ++k) p += er[k] * Ws[(g * 32 + k) * 16 + j];
  p += __shfl_xor(p, 16);
  p += __shfl_xor(p, 32);
  p += bfs[j];
  float mx = p;
#pragma unroll
  for (int o = 1; o < 16; o <<= 1) mx = fmaxf(mx, __shfl_xor(mx, o));
  float ex = expf(p - mx);
  float sm = ex;
#pragma unroll
  for (int o = 1; o < 16; o <<= 1) sm += __shfl_xor(sm, o);
  float res = p - mx - logf(sm);
  if (lane < 16) out[(size_t)node * 16 + j] = res;
}

// ---------------- launch ----------------

extern "C" void kernel_launch(void* const* d_in, const int* in_sizes, int n_in,
                              void* d_out, int out_size, void* d_ws, size_t ws_size,
                              hipStream_t stream) {
  const float* x   = (const float*)d_in[0];
  const int*   ei  = (const int*)d_in[1];
  const float* W1  = (const float*)d_in[2];
  const float* b1  = (const float*)d_in[3];
  const float* W2  = (const float*)d_in[4];
  const float* b2  = (const float*)d_in[5];
  const float* W3  = (const float*)d_in[6];
  const float* b3  = (const float*)d_in[7];
  const float* Wp1 = (const float*)d_in[8];
  const float* bp1 = (const float*)d_in[9];
  const float* Wp2 = (const float*)d_in[10];
  const float* bp2 = (const float*)d_in[11];

  const int N = in_sizes[0] / 128;
  const int E = in_sizes[1] / 2;
  const int* src = ei;       // edge_index[0]
  const int* dst = ei + E;   // edge_index[1]

  float* out    = (float*)d_out;
  float* emb    = out;                    // [N,128] final embedding
  float* scores = out + (size_t)N * 128;  // [N,16]

  char* w = (char*)d_ws;
  auto alloc = [&](size_t bytes) {
    char* p = w;
    w += (bytes + 255) & ~(size_t)255;
    return p;
  };
  int*    cnt     = (int*)alloc((size_t)N * 4);
  int*    cursor  = (int*)alloc((size_t)N * 4);
  int*    rowptr  = (int*)alloc(((size_t)N + 1) * 4);
  float*  dinv    = (float*)alloc((size_t)N * 4);
  int2*   csr     = (int2*)alloc((size_t)E * 8);          // packed (src, w)
  ushort* Hb      = (ushort*)alloc((size_t)N * 128 * 2);  // gemm out (bf16)
  ushort* Ab      = (ushort*)alloc((size_t)N * 128 * 2);  // agg out (bf16)
  ushort* Wb1     = (ushort*)alloc(16384 * 2);
  ushort* Wb2     = (ushort*)alloc(16384 * 2);
  ushort* Wb3     = (ushort*)alloc(16384 * 2);
  float*  Wf      = (float*)alloc(2048 * 4);
  float*  bf      = (float*)alloc(16 * 4);
  int*    bsum    = (int*)alloc(256 * 4);
  int*    boff    = (int*)alloc(256 * 4);

  int gE = (E + 255) / 256;
  int chunk = (N + 255) / 256;  // <= 256 required (N <= 65536)

  zero_ints<<<(N + 255) / 256, 256, 0, stream>>>(cnt, N);
  count_dst<<<gE, 256, 0, stream>>>(dst, cnt, E);
  scan_blocksums<<<256, 256, 0, stream>>>(cnt, bsum, N, chunk);
  scan_offsets<<<1, 256, 0, stream>>>(bsum, boff, rowptr, N);
  scan_write<<<256, 256, 0, stream>>>(cnt, boff, rowptr, cursor, dinv, N, chunk);
  fill_csr<<<gE, 256, 0, stream>>>(src, dst, dinv, cursor, csr, E);
  transform_w<<<3, 256, 0, stream>>>(W1, W2, W3, Wb1, Wb2, Wb3);
  fuse_w<<<1, 256, 0, stream>>>(Wp1, bp1, Wp2, bp2, Wf, bf);

  int gemm_grid = (N + 63) / 64;
  int node_grid = (N + 3) / 4;
  gemm_mfma<true><<<gemm_grid, 256, 0, stream>>>(x, Wb1, Hb, N);
  agg_csr<<<node_grid, 256, 0, stream>>>(Hb, csr, rowptr, dinv, b1, nullptr, Ab, N);
  gemm_mfma<false><<<gemm_grid, 256, 0, stream>>>(Ab, Wb2, Hb, N);
  agg_csr<<<node_grid, 256, 0, stream>>>(Hb, csr, rowptr, dinv, b2, nullptr, Ab, N);
  gemm_mfma<false><<<gemm_grid, 256, 0, stream>>>(Ab, Wb3, Hb, N);
  agg_csr<<<node_grid, 256, 0, stream>>>(Hb, csr, rowptr, dinv, b3, emb, nullptr, N);
  proj_kernel<<<node_grid, 256, 0, stream>>>(emb, Wf, bf, scores, N);
}